// Round 3
// baseline (495.868 us; speedup 1.0000x reference)
//
#include <hip/hip_runtime.h>
#include <hip/hip_bf16.h>

#define BB   16384
#define F    40
#define LDQ  72   // QB stride: 144 B = 9*16 B, 2-way max on b128 reads (free)
#define LDV  56   // VT stride: 112 B = 7*16 B, 2-way max on b128 reads (free)
#define ITER 4

typedef __bf16 bf16;
typedef __bf16 bf16x8 __attribute__((ext_vector_type(8)));
typedef __bf16 bf16x4 __attribute__((ext_vector_type(4)));
typedef float  f32x4  __attribute__((ext_vector_type(4)));

// MFMA 16x16x32 bf16 layouts:
//   A-frag: lane holds A[m = lane&15][k = (lane>>4)*8 + j]
//   B-frag: lane holds B[k = (lane>>4)*8 + j][n = lane&15]
//   C/D   : lane holds C[row = (lane>>4)*4 + r][col = lane&15]
// B-frag of M == A-frag of M^T, so xf (A-frag of X) doubles as B-operand (X^T).

__device__ __forceinline__ bf16x8 cvt8(float4 a, float4 b) {
    bf16x8 f;
    f[0] = (bf16)a.x; f[1] = (bf16)a.y; f[2] = (bf16)a.z; f[3] = (bf16)a.w;
    f[4] = (bf16)b.x; f[5] = (bf16)b.y; f[6] = (bf16)b.z; f[7] = (bf16)b.w;
    return f;
}

// ---- prep: block0 computes G = Wq*Wk^T via MFMA and packs it; blocks 1,2 pack Wv/Wr ----
// B-frag pack: ws[base + ((nt*2+kt)*64 + lane)*8 + j] = M[kt*32+(lane>>4)*8+j][nt*16+(lane&15)]
__global__ __launch_bounds__(256)
void prep_weights(const float* __restrict__ Wq, const float* __restrict__ Wk,
                  const float* __restrict__ Wv, const float* __restrict__ Wr,
                  bf16* __restrict__ ws)
{
    const int tid = threadIdx.x;
    if (blockIdx.x > 0) {
        const float* W = (blockIdx.x == 1) ? Wv : Wr;
        bf16* dst = ws + 4096 * blockIdx.x;
        for (int f = tid; f < 4096; f += 256) {
            int j = f & 7, ln = (f >> 3) & 63, kt = (f >> 9) & 1, nt = f >> 10;
            dst[f] = (bf16)W[(kt * 32 + (ln >> 4) * 8 + j) * 64 + nt * 16 + (ln & 15)];
        }
        return;
    }
    __shared__ float Gs[64 * 64];
    if (tid < 64) {   // one wave: G[d][d'] = sum_e Wq[d][e] * Wk[d'][e]
        const int l16 = tid & 15, quad = tid >> 4;
        bf16x8 aq[4][2], ak[4][2];
        #pragma unroll
        for (int mt = 0; mt < 4; ++mt)
            #pragma unroll
            for (int kt = 0; kt < 2; ++kt) {
                const float* pq = Wq + (mt * 16 + l16) * 64 + kt * 32 + quad * 8;
                const float* pk = Wk + (mt * 16 + l16) * 64 + kt * 32 + quad * 8;
                aq[mt][kt] = cvt8(*(const float4*)pq, *(const float4*)(pq + 4));
                ak[mt][kt] = cvt8(*(const float4*)pk, *(const float4*)(pk + 4));
            }
        #pragma unroll
        for (int mt = 0; mt < 4; ++mt)
            #pragma unroll
            for (int nt = 0; nt < 4; ++nt) {
                f32x4 acc = {0.f, 0.f, 0.f, 0.f};
                acc = __builtin_amdgcn_mfma_f32_16x16x32_bf16(aq[mt][0], ak[nt][0], acc, 0, 0, 0);
                acc = __builtin_amdgcn_mfma_f32_16x16x32_bf16(aq[mt][1], ak[nt][1], acc, 0, 0, 0);
                #pragma unroll
                for (int r = 0; r < 4; ++r)
                    Gs[(mt * 16 + quad * 4 + r) * 64 + nt * 16 + l16] = acc[r];
            }
    }
    __syncthreads();
    for (int f = tid; f < 4096; f += 256) {
        int j = f & 7, ln = (f >> 3) & 63, kt = (f >> 9) & 1, nt = f >> 10;
        ws[f] = (bf16)Gs[(kt * 32 + (ln >> 4) * 8 + j) * 64 + nt * 16 + (ln & 15)];
    }
}

// ---- main: 1 wave/block, ITER batches/wave, prefetched X, no barriers ----
__global__ __launch_bounds__(64, 3)
void attn_fused(const float* __restrict__ X, const bf16* __restrict__ wfrag,
                float* __restrict__ Out)
{
    __shared__ bf16 QB[40 * LDQ];       // q' = X@G, then P
    __shared__ bf16 VT[64 * LDV + 8];   // v^T: VT[e][k'], k' in [0,48) written

    const int lane = threadIdx.x;
    const int l16  = lane & 15;
    const int quad = lane >> 4;

    // zero VT k' in [48,56) on every e-row + 8-el tail: read by PV (multiplied by
    // P[k'>=48]=0) so must be finite; uninit LDS could hold NaN patterns.
    {
        bf16x8 z = {};
        *(bf16x8*)&VT[lane * LDV + 48] = z;
        if (lane == 0) *(bf16x8*)&VT[64 * LDV] = z;
    }

    const bf16x8* gF = (const bf16x8*)wfrag;   // G  B-frags
    const bf16x8* vF = gF + 512;               // Wv B-frags
    const bf16x8* rF = gF + 1024;              // Wr B-frags

    const size_t b0 = (size_t)blockIdx.x * ITER;

    float4 pA[3][2], pB[3][2];                 // prefetch regs
    {
        const float* Xb = X + b0 * (F * 64);
        #pragma unroll
        for (int mt = 0; mt < 3; ++mt) {
            int row = mt * 16 + l16; if (row >= F) row = F - 1;
            #pragma unroll
            for (int kt = 0; kt < 2; ++kt) {
                const float* p = Xb + row * 64 + kt * 32 + quad * 8;
                pA[mt][kt] = *(const float4*)p;
                pB[mt][kt] = *(const float4*)(p + 4);
            }
        }
    }

    #pragma unroll 1   // keep rolled: small I$ body, prefetch spans full body
    for (int it = 0; it < ITER; ++it) {
        bf16x8 xf[3][2];
        #pragma unroll
        for (int mt = 0; mt < 3; ++mt)
            #pragma unroll
            for (int kt = 0; kt < 2; ++kt)
                xf[mt][kt] = cvt8(pA[mt][kt], pB[mt][kt]);

        if (it + 1 < ITER) {   // prefetch next batch; lands during this body
            const float* Xb = X + (b0 + it + 1) * (F * 64);
            #pragma unroll
            for (int mt = 0; mt < 3; ++mt) {
                int row = mt * 16 + l16; if (row >= F) row = F - 1;
                #pragma unroll
                for (int kt = 0; kt < 2; ++kt) {
                    const float* p = Xb + row * 64 + kt * 32 + quad * 8;
                    pA[mt][kt] = *(const float4*)p;
                    pB[mt][kt] = *(const float4*)(p + 4);
                }
            }
        }

        // ---- q' = X @ G -> QB rows [0,40) ----
        #pragma unroll
        for (int nt = 0; nt < 4; ++nt) {
            bf16x8 g0 = gF[(nt * 2 + 0) * 64 + lane];
            bf16x8 g1 = gF[(nt * 2 + 1) * 64 + lane];
            #pragma unroll
            for (int mt = 0; mt < 3; ++mt) {
                f32x4 acc = {0.f, 0.f, 0.f, 0.f};
                acc = __builtin_amdgcn_mfma_f32_16x16x32_bf16(xf[mt][0], g0, acc, 0, 0, 0);
                acc = __builtin_amdgcn_mfma_f32_16x16x32_bf16(xf[mt][1], g1, acc, 0, 0, 0);
                int col = nt * 16 + l16, r0 = mt * 16 + quad * 4;
                #pragma unroll
                for (int r = 0; r < 4; ++r)
                    if (r0 + r < F) QB[(r0 + r) * LDQ + col] = (bf16)acc[r];
            }
        }

        // ---- v = X @ Wv -> VT transposed (k' rows 40..47 garbage-but-finite) ----
        #pragma unroll
        for (int nt = 0; nt < 4; ++nt) {
            bf16x8 v0 = vF[(nt * 2 + 0) * 64 + lane];
            bf16x8 v1 = vF[(nt * 2 + 1) * 64 + lane];
            #pragma unroll
            for (int mt = 0; mt < 3; ++mt) {
                f32x4 acc = {0.f, 0.f, 0.f, 0.f};
                acc = __builtin_amdgcn_mfma_f32_16x16x32_bf16(xf[mt][0], v0, acc, 0, 0, 0);
                acc = __builtin_amdgcn_mfma_f32_16x16x32_bf16(xf[mt][1], v1, acc, 0, 0, 0);
                bf16x4 pk;
                pk[0] = (bf16)acc[0]; pk[1] = (bf16)acc[1];
                pk[2] = (bf16)acc[2]; pk[3] = (bf16)acc[3];
                *(bf16x4*)&VT[(nt * 16 + l16) * LDV + mt * 16 + quad * 4] = pk;
            }
        }

        // ---- per-smt: S row-strip, softmax (no max pass: |s| <~ 8), P -> QB ----
        const bool mask2 = (l16 >= 8);   // cols 40..47 invalid
        #pragma unroll
        for (int smt = 0; smt < 3; ++smt) {
            int qrow = smt * 16 + l16; if (qrow >= F) qrow = F - 1;
            bf16x8 q0 = *(const bf16x8*)&QB[qrow * LDQ + 0  + quad * 8];
            bf16x8 q1 = *(const bf16x8*)&QB[qrow * LDQ + 32 + quad * 8];
            f32x4 sa[3];
            #pragma unroll
            for (int snt = 0; snt < 3; ++snt) {
                f32x4 acc = {0.f, 0.f, 0.f, 0.f};
                acc = __builtin_amdgcn_mfma_f32_16x16x32_bf16(q0, xf[snt][0], acc, 0, 0, 0);
                acc = __builtin_amdgcn_mfma_f32_16x16x32_bf16(q1, xf[snt][1], acc, 0, 0, 0);
                sa[snt] = acc;
            }
            #pragma unroll
            for (int r = 0; r < 4; ++r) {
                float e0 = __expf(sa[0][r]);
                float e1 = __expf(sa[1][r]);
                float e2 = mask2 ? 0.f : __expf(sa[2][r]);
                float sum = e0 + e1 + e2;
                #pragma unroll
                for (int off = 1; off < 16; off <<= 1)
                    sum += __shfl_xor(sum, off, 64);
                float inv = 1.0f / sum;
                int row = smt * 16 + quad * 4 + r;
                if (row < F) {
                    QB[row * LDQ + l16]      = (bf16)(e0 * inv);
                    QB[row * LDQ + 16 + l16] = (bf16)(e1 * inv);
                    QB[row * LDQ + 32 + l16] = (bf16)(e2 * inv);  // 0 for cols>=40
                    QB[row * LDQ + 48 + l16] = (bf16)0.f;         // K-pad of PV
                }
            }
        }

        // ---- O = X@Wr + P@v (residual fused as leading MFMAs), relu, store ----
        bf16x8 pf[3][2];
        #pragma unroll
        for (int mt = 0; mt < 3; ++mt) {
            int prow = mt * 16 + l16; if (prow >= F) prow = F - 1;
            pf[mt][0] = *(const bf16x8*)&QB[prow * LDQ + 0  + quad * 8];
            pf[mt][1] = *(const bf16x8*)&QB[prow * LDQ + 32 + quad * 8];
        }
        #pragma unroll
        for (int nt = 0; nt < 4; ++nt) {
            bf16x8 r0f = rF[(nt * 2 + 0) * 64 + lane];
            bf16x8 r1f = rF[(nt * 2 + 1) * 64 + lane];
            bf16x8 v0  = *(const bf16x8*)&VT[(nt * 16 + l16) * LDV + 0  + quad * 8];
            bf16x8 v1  = *(const bf16x8*)&VT[(nt * 16 + l16) * LDV + 32 + quad * 8];
            #pragma unroll
            for (int mt = 0; mt < 3; ++mt) {
                f32x4 acc = {0.f, 0.f, 0.f, 0.f};
                acc = __builtin_amdgcn_mfma_f32_16x16x32_bf16(xf[mt][0], r0f, acc, 0, 0, 0);
                acc = __builtin_amdgcn_mfma_f32_16x16x32_bf16(xf[mt][1], r1f, acc, 0, 0, 0);
                acc = __builtin_amdgcn_mfma_f32_16x16x32_bf16(pf[mt][0], v0, acc, 0, 0, 0);
                acc = __builtin_amdgcn_mfma_f32_16x16x32_bf16(pf[mt][1], v1, acc, 0, 0, 0);
                int col = nt * 16 + l16;
                #pragma unroll
                for (int r = 0; r < 4; ++r) {
                    int row = mt * 16 + quad * 4 + r;
                    if (row < F)
                        Out[(b0 + it) * (size_t)(F * 64) + row * 64 + col] = fmaxf(acc[r], 0.f);
                }
            }
        }
    }
}

extern "C" void kernel_launch(void* const* d_in, const int* in_sizes, int n_in,
                              void* d_out, int out_size, void* d_ws, size_t ws_size,
                              hipStream_t stream) {
    const float* X  = (const float*)d_in[0];
    const float* Wq = (const float*)d_in[1];
    const float* Wk = (const float*)d_in[2];
    const float* Wv = (const float*)d_in[3];
    const float* Wr = (const float*)d_in[4];
    float* Out = (float*)d_out;
    bf16* ws = (bf16*)d_ws;   // 12288 bf16 fragment-packed G/Wv/Wr

    prep_weights<<<3, 256, 0, stream>>>(Wq, Wk, Wv, Wr, ws);
    attn_fused<<<BB / ITER, 64, 0, stream>>>(X, ws, Out);
}

// Round 5
// 315.544 us; speedup vs baseline: 1.5715x; 1.5715x over previous
//
#include <hip/hip_runtime.h>
#include <hip/hip_bf16.h>

#define BB  16384
#define F   40
#define LDQ 72   // QB stride (el): 144 B = 9*16 B, 16B-aligned rows
#define LDV 56   // VT stride (el): 112 B = 7*16 B, 16B-aligned rows

typedef __bf16 bf16;
typedef __bf16 bf16x8 __attribute__((ext_vector_type(8)));
typedef __bf16 bf16x4 __attribute__((ext_vector_type(4)));
typedef float  f32x4  __attribute__((ext_vector_type(4)));

// MFMA 16x16x32 bf16 layouts:
//   A-frag: lane holds A[m = lane&15][k = (lane>>4)*8 + j]
//   B-frag: lane holds B[k = (lane>>4)*8 + j][n = lane&15]
//   C/D   : lane holds C[row = (lane>>4)*4 + r][col = lane&15]
// B-frag(M) == A-frag(M^T); mfma(B,A) computes the transposed product.
// We use this to make every producer emit 4-consecutive-element packs.

__device__ __forceinline__ bf16x8 cvt8(float4 a, float4 b) {
    bf16x8 f;
    f[0] = (bf16)a.x; f[1] = (bf16)a.y; f[2] = (bf16)a.z; f[3] = (bf16)a.w;
    f[4] = (bf16)b.x; f[5] = (bf16)b.y; f[6] = (bf16)b.z; f[7] = (bf16)b.w;
    return f;
}

// ---- prep: block0 computes G = Wq*Wk^T via MFMA and packs it; blocks 1,2 pack Wv/Wr ----
// B-frag pack: ws[base + ((nt*2+kt)*64 + lane)*8 + j] = M[kt*32+(lane>>4)*8+j][nt*16+(lane&15)]
__global__ __launch_bounds__(256)
void prep_weights(const float* __restrict__ Wq, const float* __restrict__ Wk,
                  const float* __restrict__ Wv, const float* __restrict__ Wr,
                  bf16* __restrict__ ws)
{
    const int tid = threadIdx.x;
    if (blockIdx.x > 0) {
        const float* W = (blockIdx.x == 1) ? Wv : Wr;
        bf16* dst = ws + 4096 * blockIdx.x;
        for (int f = tid; f < 4096; f += 256) {
            int j = f & 7, ln = (f >> 3) & 63, kt = (f >> 9) & 1, nt = f >> 10;
            dst[f] = (bf16)W[(kt * 32 + (ln >> 4) * 8 + j) * 64 + nt * 16 + (ln & 15)];
        }
        return;
    }
    __shared__ float Gs[64 * 64];
    if (tid < 64) {   // one wave: G[d][d'] = sum_e Wq[d][e] * Wk[d'][e]
        const int l16 = tid & 15, quad = tid >> 4;
        bf16x8 aq[4][2], ak[4][2];
        #pragma unroll
        for (int mt = 0; mt < 4; ++mt)
            #pragma unroll
            for (int kt = 0; kt < 2; ++kt) {
                const float* pq = Wq + (mt * 16 + l16) * 64 + kt * 32 + quad * 8;
                const float* pk = Wk + (mt * 16 + l16) * 64 + kt * 32 + quad * 8;
                aq[mt][kt] = cvt8(*(const float4*)pq, *(const float4*)(pq + 4));
                ak[mt][kt] = cvt8(*(const float4*)pk, *(const float4*)(pk + 4));
            }
        #pragma unroll
        for (int mt = 0; mt < 4; ++mt)
            #pragma unroll
            for (int nt = 0; nt < 4; ++nt) {
                f32x4 acc = {0.f, 0.f, 0.f, 0.f};
                acc = __builtin_amdgcn_mfma_f32_16x16x32_bf16(aq[mt][0], ak[nt][0], acc, 0, 0, 0);
                acc = __builtin_amdgcn_mfma_f32_16x16x32_bf16(aq[mt][1], ak[nt][1], acc, 0, 0, 0);
                #pragma unroll
                for (int r = 0; r < 4; ++r)
                    Gs[(mt * 16 + quad * 4 + r) * 64 + nt * 16 + l16] = acc[r];
            }
    }
    __syncthreads();
    for (int f = tid; f < 4096; f += 256) {
        int j = f & 7, ln = (f >> 3) & 63, kt = (f >> 9) & 1, nt = f >> 10;
        ws[f] = (bf16)Gs[(kt * 32 + (ln >> 4) * 8 + j) * 64 + nt * 16 + (ln & 15)];
    }
}

// ---- main: 1 wave/block, 1 batch/block (R2's L3-friendly order), no barriers ----
__global__ __launch_bounds__(64, 3)
void attn_fused(const float* __restrict__ X, const bf16* __restrict__ wfrag,
                float* __restrict__ Out)
{
    __shared__ bf16 QB[48 * LDQ];        // q' rows [m][e], later P rows [m][k']
    __shared__ bf16 VT[64 * LDV + 8];    // v^T [e][k']; k' 48..55 kept zero, 8-el tail zero

    const int lane = threadIdx.x;        // 0..63
    const int l16  = lane & 15;
    const int quad = lane >> 4;
    const int b    = blockIdx.x;
    const float* Xb = X + (size_t)b * (F * 64);

    // VT pad: cols 48..55 of every e-row + tail must be finite (read by PV A-side,
    // multiplied by P^T zeros). v-stores never touch cols >= 48, so zero once.
    {
        bf16x8 z = {};
        *(bf16x8*)&VT[lane * LDV + 48] = z;
        if (lane == 0) *(bf16x8*)&VT[64 * LDV] = z;
    }

    // ---- X A-fragments straight from global (fp32 -> bf16), row-clamped ----
    bf16x8 xf[3][2];
    #pragma unroll
    for (int mt = 0; mt < 3; ++mt) {
        int row = mt * 16 + l16; if (row >= F) row = F - 1;  // finite pad rows
        #pragma unroll
        for (int kt = 0; kt < 2; ++kt) {
            const float* p = Xb + row * 64 + kt * 32 + quad * 8;
            xf[mt][kt] = cvt8(*(const float4*)p, *(const float4*)(p + 4));
        }
    }

    const bf16x8* gF = (const bf16x8*)wfrag;   // B-frags of G  == A-frags of G^T
    const bf16x8* vF = gF + 512;               // B-frags of Wv
    const bf16x8* rF = gF + 1024;              // B-frags of Wr == A-frags of Wr^T

    // ---- q'^T = G^T @ X^T : C-layout lane = q'[m=col][e=4 consecutive rows] ----
    // -> ds_write_b64 per tile (12 total), QB[m][e] row-major
    #pragma unroll
    for (int mt = 0; mt < 4; ++mt) {           // e-tiles (M-dim of q'^T)
        bf16x8 a0 = gF[(mt * 2 + 0) * 64 + lane];
        bf16x8 a1 = gF[(mt * 2 + 1) * 64 + lane];
        #pragma unroll
        for (int nt = 0; nt < 3; ++nt) {       // m-tiles (N-dim)
            f32x4 acc = {0.f, 0.f, 0.f, 0.f};
            acc = __builtin_amdgcn_mfma_f32_16x16x32_bf16(a0, xf[nt][0], acc, 0, 0, 0);
            acc = __builtin_amdgcn_mfma_f32_16x16x32_bf16(a1, xf[nt][1], acc, 0, 0, 0);
            bf16x4 pk;
            pk[0] = (bf16)acc[0]; pk[1] = (bf16)acc[1];
            pk[2] = (bf16)acc[2]; pk[3] = (bf16)acc[3];
            *(bf16x4*)&QB[(nt * 16 + l16) * LDQ + mt * 16 + quad * 4] = pk;
        }
    }

    // ---- v = X @ Wv : C-layout lane = v[k'=4 consecutive][e=col] -> VT[e][k'] b64 ----
    #pragma unroll
    for (int nt = 0; nt < 4; ++nt) {           // e-tiles
        bf16x8 b0 = vF[(nt * 2 + 0) * 64 + lane];
        bf16x8 b1 = vF[(nt * 2 + 1) * 64 + lane];
        #pragma unroll
        for (int mt = 0; mt < 3; ++mt) {       // k'-tiles
            f32x4 acc = {0.f, 0.f, 0.f, 0.f};
            acc = __builtin_amdgcn_mfma_f32_16x16x32_bf16(xf[mt][0], b0, acc, 0, 0, 0);
            acc = __builtin_amdgcn_mfma_f32_16x16x32_bf16(xf[mt][1], b1, acc, 0, 0, 0);
            bf16x4 pk;
            pk[0] = (bf16)acc[0]; pk[1] = (bf16)acc[1];
            pk[2] = (bf16)acc[2]; pk[3] = (bf16)acc[3];
            *(bf16x4*)&VT[(nt * 16 + l16) * LDV + mt * 16 + quad * 4] = pk;
        }
    }

    // ---- S^T = X @ q'^T : A = xf (k'-rows), B = A-frag of q' from QB ----
    bf16x8 qf[3][2];
    #pragma unroll
    for (int nt = 0; nt < 3; ++nt) {
        qf[nt][0] = *(const bf16x8*)&QB[(nt * 16 + l16) * LDQ + 0  + quad * 8];
        qf[nt][1] = *(const bf16x8*)&QB[(nt * 16 + l16) * LDQ + 32 + quad * 8];
    }
    f32x4 sacc[3][3];   // [mt_k'][nt_m]
    #pragma unroll
    for (int mt = 0; mt < 3; ++mt)
        #pragma unroll
        for (int nt = 0; nt < 3; ++nt) {
            f32x4 acc = {0.f, 0.f, 0.f, 0.f};
            acc = __builtin_amdgcn_mfma_f32_16x16x32_bf16(xf[mt][0], qf[nt][0], acc, 0, 0, 0);
            acc = __builtin_amdgcn_mfma_f32_16x16x32_bf16(xf[mt][1], qf[nt][1], acc, 0, 0, 0);
            sacc[mt][nt] = acc;
        }

    // ---- softmax over k' (rows of S^T): in-lane 12 values + 2 shfls; P -> QB b64 ----
    // lane holds S^T[k' = 16mt+4*quad+r][m = 16nt+l16]; k' >= 40 <=> mt==2 && quad>=2.
    // No max pass: |s| small (q'=XG, std ~1.3), exp fp32-safe (validated R2/R3).
    const bool dead = (quad >= 2);
    #pragma unroll
    for (int nt = 0; nt < 3; ++nt) {
        float ex[3][4]; float sum = 0.f;
        #pragma unroll
        for (int mt = 0; mt < 3; ++mt)
            #pragma unroll
            for (int r = 0; r < 4; ++r) {
                float e = (mt == 2 && dead) ? 0.f : __expf(sacc[mt][nt][r]);
                ex[mt][r] = e; sum += e;
            }
        sum += __shfl_xor(sum, 16, 64);
        sum += __shfl_xor(sum, 32, 64);
        float inv = 1.0f / sum;
        #pragma unroll
        for (int mt = 0; mt < 3; ++mt) {
            bf16x4 pk;
            pk[0] = (bf16)(ex[mt][0] * inv); pk[1] = (bf16)(ex[mt][1] * inv);
            pk[2] = (bf16)(ex[mt][2] * inv); pk[3] = (bf16)(ex[mt][3] * inv);
            *(bf16x4*)&QB[(nt * 16 + l16) * LDQ + mt * 16 + quad * 4] = pk;
        }
    }

    // ---- O^T = Wr^T@X^T + V^T@P^T ; C-layout lane = O[m=col][e=4 consec] -> dwordx4 ----
    f32x4 oacc[4][3];
    #pragma unroll
    for (int mt = 0; mt < 4; ++mt) {           // e-tiles
        bf16x8 a0 = rF[(mt * 2 + 0) * 64 + lane];
        bf16x8 a1 = rF[(mt * 2 + 1) * 64 + lane];
        #pragma unroll
        for (int nt = 0; nt < 3; ++nt) {       // m-tiles
            f32x4 acc = {0.f, 0.f, 0.f, 0.f};
            acc = __builtin_amdgcn_mfma_f32_16x16x32_bf16(a0, xf[nt][0], acc, 0, 0, 0);
            acc = __builtin_amdgcn_mfma_f32_16x16x32_bf16(a1, xf[nt][1], acc, 0, 0, 0);
            oacc[mt][nt] = acc;
        }
    }
    // P^T B-frags (== A-frag of P): kt=1 quads>=2 would read stale q' cols 48..63 -> zero in regs
    bf16x8 ptf[3][2];
    #pragma unroll
    for (int nt = 0; nt < 3; ++nt) {
        ptf[nt][0] = *(const bf16x8*)&QB[(nt * 16 + l16) * LDQ + 0  + quad * 8];
        bf16x8 t   = *(const bf16x8*)&QB[(nt * 16 + l16) * LDQ + 32 + quad * 8];
        if (dead) t = bf16x8{};
        ptf[nt][1] = t;
    }
    #pragma unroll
    for (int mt = 0; mt < 4; ++mt) {
        bf16x8 v0 = *(const bf16x8*)&VT[(mt * 16 + l16) * LDV + 0  + quad * 8];
        bf16x8 v1 = *(const bf16x8*)&VT[(mt * 16 + l16) * LDV + 32 + quad * 8];
        #pragma unroll
        for (int nt = 0; nt < 3; ++nt) {
            f32x4 acc = oacc[mt][nt];
            acc = __builtin_amdgcn_mfma_f32_16x16x32_bf16(v0, ptf[nt][0], acc, 0, 0, 0);
            acc = __builtin_amdgcn_mfma_f32_16x16x32_bf16(v1, ptf[nt][1], acc, 0, 0, 0);
            int m = nt * 16 + l16;
            if (m < F) {
                f32x4 st;
                st[0] = fmaxf(acc[0], 0.f); st[1] = fmaxf(acc[1], 0.f);
                st[2] = fmaxf(acc[2], 0.f); st[3] = fmaxf(acc[3], 0.f);
                // nontemporal: output is write-once; keep it out of L2/L3 so X stays resident.
                // ext_vector f32x4 (not HIP float4 class) — builtin requires a real vector type.
                __builtin_nontemporal_store(st,
                    (f32x4*)&Out[(size_t)b * (F * 64) + m * 64 + mt * 16 + quad * 4]);
            }
        }
    }
}

extern "C" void kernel_launch(void* const* d_in, const int* in_sizes, int n_in,
                              void* d_out, int out_size, void* d_ws, size_t ws_size,
                              hipStream_t stream) {
    const float* X  = (const float*)d_in[0];
    const float* Wq = (const float*)d_in[1];
    const float* Wk = (const float*)d_in[2];
    const float* Wv = (const float*)d_in[3];
    const float* Wr = (const float*)d_in[4];
    float* Out = (float*)d_out;
    bf16* ws = (bf16*)d_ws;   // 12288 bf16 fragment-packed G/Wv/Wr

    prep_weights<<<3, 256, 0, stream>>>(Wq, Wk, Wv, Wr, ws);
    attn_fused<<<BB, 64, 0, stream>>>(X, ws, Out);
}